// Round 12
// baseline (89.756 us; speedup 1.0000x reference)
//
#include <hip/hip_runtime.h>
#include <math.h>

#define BATCH 16
#define H 1024
#define W 1024
#define NTILES 8192      // 16 img * 512 tiles (32x64)
#define NBANDS (NTILES * 4)   // 8-row x 64-col wave bands
#define CAP 4096
#define TOPK 2048
#define BCW 12           // per-band candidate cap (8-separation bound: 8)

struct WS {
  float pt1[NBANDS];               // per-band dense partials (always stored)
  int   pmc[NBANDS];
  int   band_cnt[NBANDS];          // always stored
  float corr_part[BATCH * 64];     // per (image,slice) stamp partial (always stored)
  float band_val[NBANDS * BCW];
  int   band_idx[NBANDS * BCW];
};

// ks=7 sigma=1 normalized Gaussian (validated absmax 0.0 R1-R11)
__constant__ float GW[7] = {
  0.004433048175f, 0.054005582623f, 0.242036229376f, 0.399050279652f,
  0.242036229376f, 0.054005582623f, 0.004433048175f
};

__device__ __forceinline__ float4 max4(float4 a, float4 b) {
  float4 r;
  r.x = fmaxf(a.x, b.x); r.y = fmaxf(a.y, b.y);
  r.z = fmaxf(a.z, b.z); r.w = fmaxf(a.w, b.w);
  return r;
}

// ZERO s_barrier: each wave independently processes an 8-row x 64-col band
// from its OWN 7.4KB halo slice. Only wave-local sync (no vmcnt drain).
__global__ __launch_bounds__(256, 5) void k_nms(const float* __restrict__ score1,
                                                const float* __restrict__ score2,
                                                const int* __restrict__ mask,
                                                WS* __restrict__ ws) {
  __shared__ float4 halo[4][22][21];   // per-wave slice: 22 rows x 20(+1 pad) f4
  const int tid = threadIdx.x;
  const int w = tid >> 6, l = tid & 63;

  // bijective XCD swizzle (kept: cut FETCH 129->98MB in R7)
  const int t = (blockIdx.x & 7) * (NTILES / 8) + (blockIdx.x >> 3);
  const int b  = t >> 9;
  const int tt = t & 511;
  const int ty0 = (tt >> 4) << 5;
  const int tx0 = (tt & 15) << 6;
  const int by0 = ty0 + (w << 3);      // this wave's band start row
  const size_t ibase = (size_t)b * ((size_t)H * W);
  const float* s2 = score2 + ibase;

  // ---- issue s1/mask FIRST (dense term waits only on these, halo stays in flight) ----
  const int rl = l >> 3;               // local band row 0..7
  const int c8 = l & 7;                // col group: cols c8*8 .. c8*8+7
  const size_t pb = ibase + (size_t)(by0 + rl) * W + tx0 + (c8 << 3);
  const float4 s1a = *(const float4*)(score1 + pb);
  const float4 s1b = *(const float4*)(score1 + pb + 4);
  const int4  mka = *(const int4*)(mask + pb);
  const int4  mkb = *(const int4*)(mask + pb + 4);

  // ---- issue this wave's halo: 22 rows x 80 cols, clamped vector loads ----
  float4 st[7]; int sr[7], sc[7];
  #pragma unroll
  for (int k = 0; k < 7; k++) {
    const int slot = l + (k << 6);
    if (slot < 440) {
      const int r = slot / 20, c = slot - r * 20;
      sr[k] = r; sc[k] = c;
      const int gy = by0 - 7 + r, gx = tx0 - 8 + (c << 2);
      const bool ok = (gy >= 0) & (gy < H) & (gx >= 0) & (gx < W);
      const int gyc = min(max(gy, 0), H - 1);
      const int gxc = ok ? gx : 0;
      float4 v = *(const float4*)(s2 + (size_t)gyc * W + gxc);
      if (!ok) v = make_float4(-INFINITY, -INFINITY, -INFINITY, -INFINITY);
      st[k] = v;
    }
  }

  // dense term (consumes s1/mask only)
  float t1 = 0.f; int mcnt = 0; unsigned int mbits = 0;
  {
    const float sc_[8] = {s1a.x, s1a.y, s1a.z, s1a.w, s1b.x, s1b.y, s1b.z, s1b.w};
    const int   mm[8] = {mka.x, mka.y, mka.z, mka.w, mkb.x, mkb.y, mkb.z, mkb.w};
    #pragma unroll
    for (int j = 0; j < 8; j++) {
      if (mm[j]) { t1 = fmaf(sc_[j], sc_[j], t1); mcnt++; mbits |= (1u << j); }
    }
  }

  // stage halo into this wave's slice
  #pragma unroll
  for (int k = 0; k < 7; k++) {
    const int slot = l + (k << 6);
    if (slot < 440) halo[w][sr[k]][sc[k]] = st[k];
  }
  // wave-local sync: writes visible to all lanes of this wave (no vmcnt drain)
  __builtin_amdgcn_wave_barrier();
  asm volatile("s_waitcnt lgkmcnt(0)" ::: "memory");
  __builtin_amdgcn_sched_barrier(0);

  // ---- vertical 15-max into registers (lanes 0..39: 2 runs of 4 rows x 20 cg) ----
  float4 vr0, vr1, vr2, vr3;
  int R0 = 0, cg = 0;
  if (l < 40) {
    const int r2 = l / 20;
    cg = l - r2 * 20;
    R0 = r2 << 2;                      // local out rows R0..R0+3
    float4 core = halo[w][R0 + 3][cg];
    #pragma unroll
    for (int k = 4; k <= 14; k++) core = max4(core, halo[w][R0 + k][cg]);
    const float4 h0 = halo[w][R0][cg], h1 = halo[w][R0 + 1][cg], h2 = halo[w][R0 + 2][cg];
    const float4 h15 = halo[w][R0 + 15][cg], h16 = halo[w][R0 + 16][cg], h17 = halo[w][R0 + 17][cg];
    const float4 p2 = h2, p1 = max4(h1, p2), p0 = max4(h0, p1);
    const float4 sf15 = h15, sf16 = max4(sf15, h16), sf17 = max4(sf16, h17);
    vr0 = max4(core, p0);
    vr1 = max4(max4(core, p1), sf15);
    vr2 = max4(max4(core, p2), sf16);
    vr3 = max4(core, sf17);
  }
  // capture raw score2 centers (local rows 7..14) before overwrite
  const float4 cva = halo[w][rl + 7][(c8 << 1) + 2];
  const float4 cvb = halo[w][rl + 7][(c8 << 1) + 3];
  // all reads of rows 0..21 complete before overwriting rows 0..7
  __builtin_amdgcn_wave_barrier();
  asm volatile("s_waitcnt lgkmcnt(0)" ::: "memory");
  __builtin_amdgcn_sched_barrier(0);

  // write vertical maxes in place into local rows 0..7
  if (l < 40) {
    halo[w][R0 + 0][cg] = vr0;
    halo[w][R0 + 1][cg] = vr1;
    halo[w][R0 + 2][cg] = vr2;
    halo[w][R0 + 3][cg] = vr3;
  }
  __builtin_amdgcn_wave_barrier();
  asm volatile("s_waitcnt lgkmcnt(0)" ::: "memory");
  __builtin_amdgcn_sched_barrier(0);

  // ---- horizontal 15-max + emit ----
  float r[24];
  #pragma unroll
  for (int g = 0; g < 6; g++) {
    float4 v = halo[w][rl][(c8 << 1) + g];
    r[4 * g + 0] = v.x; r[4 * g + 1] = v.y; r[4 * g + 2] = v.z; r[4 * g + 3] = v.w;
  }
  float core = r[8];
  #pragma unroll
  for (int k = 9; k <= 15; k++) core = fmaxf(core, r[k]);
  const float q7 = r[7];
  const float q6 = fmaxf(r[6], q7);
  const float q5 = fmaxf(r[5], q6);
  const float q4 = fmaxf(r[4], q5);
  const float q3 = fmaxf(r[3], q4);
  const float q2 = fmaxf(r[2], q3);
  const float q1 = fmaxf(r[1], q2);
  float sa[7];
  sa[0] = r[16];
  #pragma unroll
  for (int k = 1; k < 7; k++) sa[k] = fmaxf(sa[k - 1], r[16 + k]);
  float pooled[8];
  pooled[0] = fmaxf(core, q1);
  pooled[1] = fmaxf(fmaxf(core, q2), sa[0]);
  pooled[2] = fmaxf(fmaxf(core, q3), sa[1]);
  pooled[3] = fmaxf(fmaxf(core, q4), sa[2]);
  pooled[4] = fmaxf(fmaxf(core, q5), sa[3]);
  pooled[5] = fmaxf(fmaxf(core, q6), sa[4]);
  pooled[6] = fmaxf(fmaxf(core, q7), sa[5]);
  pooled[7] = fmaxf(core, sa[6]);

  const float cc[8] = {cva.x, cva.y, cva.z, cva.w, cvb.x, cvb.y, cvb.z, cvb.w};
  int cj = -1; float cv = 0.f;
  #pragma unroll
  for (int j = 0; j < 8; j++) {
    if (((mbits >> j) & 1u) && cj < 0) {
      const float s = cc[j];
      if (s == pooled[j] && s > 0.f) { cj = j; cv = s; }
    }
  }
  const int band = (t << 2) + w;
  const unsigned long long bal = __ballot(cj >= 0);
  if (cj >= 0) {
    const int pos = (int)__popcll(bal & ((1ull << l) - 1ull));
    if (pos < BCW) {
      ws->band_val[band * BCW + pos] = cv;
      ws->band_idx[band * BCW + pos] = (by0 + rl) * W + tx0 + (c8 << 3) + cj;
    }
  }
  #pragma unroll
  for (int off = 32; off > 0; off >>= 1) {
    t1 += __shfl_down(t1, off);
    mcnt += __shfl_down(mcnt, off);
  }
  if (l == 0) {
    int nc = (int)__popcll(bal); if (nc > BCW) nc = BCW;
    ws->band_cnt[band] = nc;
    ws->pt1[band] = t1;
    ws->pmc[band] = mcnt;
  }
}

// Fused compaction + exact-rank + stamp (unchanged from R10/R11).
__global__ __launch_bounds__(256, 4) void k_rankstamp(const float* __restrict__ score1,
                                                      const int* __restrict__ mask,
                                                      WS* __restrict__ ws) {
  const int blk = (blockIdx.x & 7) * 128 + (blockIdx.x >> 3);
  const int b = blk >> 6;
  const int slice = blk & 63;
  __shared__ __align__(16) float sval[CAP];
  __shared__ __align__(16) int   sidx[CAP];
  __shared__ int   wt[4];
  __shared__ int   s_tot;
  __shared__ int   s_prank[4][64];
  __shared__ int   s_keys[64];
  __shared__ int   s_nk;
  __shared__ float cred[4];
  const int tid = threadIdx.x;
  const int w = tid >> 6, l = tid & 63;

  const int base = b * 2048 + tid * 8;
  int c[8]; int csum = 0;
  #pragma unroll
  for (int u = 0; u < 8; u++) {
    int x = ws->band_cnt[base + u];
    if (x > BCW) x = BCW;
    c[u] = x; csum += x;
  }
  int v = csum;
  #pragma unroll
  for (int off = 1; off < 64; off <<= 1) {
    int u2 = __shfl_up(v, off);
    if (l >= off) v += u2;
  }
  if (l == 63) wt[w] = v;
  __syncthreads();
  int wo = 0;
  #pragma unroll
  for (int k = 0; k < 4; k++) if (k < w) wo += wt[k];
  const int excl = v - csum + wo;
  if (tid == 255) {
    int tot = excl + csum;
    if (tot > CAP) tot = CAP;
    s_tot = tot;
    #pragma unroll
    for (int u = 0; u < 3; u++)
      if (tot + u < CAP) sval[tot + u] = 0.f;
  }
  int off = excl;
  #pragma unroll
  for (int u = 0; u < 8; u++) {
    const float* sv = ws->band_val + (size_t)(base + u) * BCW;
    const int*   si = ws->band_idx + (size_t)(base + u) * BCW;
    for (int j = 0; j < c[u]; j++) {
      if (off < CAP) { sval[off] = sv[j]; sidx[off] = si[j]; }
      off++;
    }
  }
  __syncthreads();

  const int n = s_tot;
  const int i0 = slice << 6;
  if (i0 >= n) {
    if (tid == 0) ws->corr_part[b * 64 + slice] = 0.f;
    return;
  }
  const int nf4 = (n + 3) >> 2;

  const float vi = sval[i0 + l];
  const int   xi = sidx[i0 + l];
  const int q = (nf4 + 3) >> 2;
  int lo = w * q; if (lo > nf4) lo = nf4;
  int hi = lo + q; if (hi > nf4) hi = nf4;
  int rank = 0;
  int j = lo;
  for (; j + 4 <= hi; j += 4) {
    #pragma unroll
    for (int u = 0; u < 4; u++) {
      const float4 vv = ((const float4*)sval)[j + u];
      const int4  iv = ((const int4*)sidx)[j + u];
      rank += (vv.x > vi) + (vv.y > vi) + (vv.z > vi) + (vv.w > vi);
      rank += (vv.x == vi && iv.x < xi);
      rank += (vv.y == vi && iv.y < xi);
      rank += (vv.z == vi && iv.z < xi);
      rank += (vv.w == vi && iv.w < xi);
    }
  }
  for (; j < hi; j++) {
    const float4 vv = ((const float4*)sval)[j];
    const int4  iv = ((const int4*)sidx)[j];
    rank += (vv.x > vi) + (vv.y > vi) + (vv.z > vi) + (vv.w > vi);
    rank += (vv.x == vi && iv.x < xi);
    rank += (vv.y == vi && iv.y < xi);
    rank += (vv.z == vi && iv.z < xi);
    rank += (vv.w == vi && iv.w < xi);
  }
  s_prank[w][l] = rank;
  __syncthreads();

  if (tid < 64) {
    const int rtot = s_prank[0][tid] + s_prank[1][tid] + s_prank[2][tid] + s_prank[3][tid];
    const bool sel = (i0 + tid < n) && (rtot < TOPK);
    const unsigned long long bal = __ballot(sel);
    if (sel) {
      const int pos = __popcll(bal & ((1ull << tid) - 1ull));
      s_keys[pos] = sidx[i0 + tid];
    }
    if (tid == 0) s_nk = (int)__popcll(bal);
  }
  __syncthreads();
  const int nk = s_nk;

  float contrib = 0.f;
  const int sub = tid & 7;
  const size_t ib2 = (size_t)b * ((size_t)H * W);
  #pragma unroll
  for (int rnd = 0; rnd < 2; rnd++) {
    const int k = (tid >> 3) + (rnd << 5);
    if (k < nk && sub < 7) {
      const int ck = s_keys[k];
      const int cy = ck >> 10, cx = ck & 1023;
      const int py = cy + sub - 3;
      const float wy = GW[sub] * ((py >= 0 && py < H) ? 1.f : 0.f);
      const int pyc = min(max(py, 0), H - 1);
      const float* s1r = score1 + ib2 + (size_t)pyc * W;
      const int*   mr  = mask   + ib2 + (size_t)pyc * W;
      #pragma unroll
      for (int dx = -3; dx <= 3; dx++) {
        const int px = cx + dx;
        const float wv = wy * GW[dx + 3] * ((px >= 0 && px < W) ? 1.f : 0.f);
        const int pxc = min(max(px, 0), W - 1);
        const float mf = (mr[pxc] != 0) ? 1.f : 0.f;
        contrib += mf * wv * (wv - 2.f * s1r[pxc]);
      }
    }
  }
  #pragma unroll
  for (int off2 = 32; off2 > 0; off2 >>= 1) contrib += __shfl_down(contrib, off2);
  if (l == 0) cred[w] = contrib;
  __syncthreads();
  if (tid == 0)
    ws->corr_part[b * 64 + slice] = (cred[0] + cred[1]) + (cred[2] + cred[3]);
}

// One block, 1024 threads: wave b reduces image b's partials (unchanged).
__global__ __launch_bounds__(1024) void k_final(WS* __restrict__ ws, float* __restrict__ out) {
  const int tid = threadIdx.x;
  const int b = tid >> 6, l = tid & 63;
  __shared__ double sD[BATCH];

  double tsum = 0.0; long long msum = 0;
  const float4* pv = (const float4*)(ws->pt1 + b * 2048);
  const int4*   pm = (const int4*)(ws->pmc + b * 2048);
  #pragma unroll
  for (int k = 0; k < 8; k++) {
    const float4 f = pv[l + (k << 6)];
    const int4   m = pm[l + (k << 6)];
    tsum += (double)f.x + (double)f.y + (double)f.z + (double)f.w;
    msum += (long long)(m.x + m.y + m.z + m.w);
  }
  double csum = (double)ws->corr_part[b * 64 + l];
  #pragma unroll
  for (int off = 32; off > 0; off >>= 1) {
    tsum += __shfl_down(tsum, off);
    msum += __shfl_down(msum, off);
    csum += __shfl_down(csum, off);
  }
  if (l == 0) {
    double denom = (double)msum;
    if (denom < 1e-8) denom = 1e-8;
    sD[b] = (tsum + csum) / denom;
  }
  __syncthreads();
  if (tid == 0) {
    double acc = 0.0;
    #pragma unroll
    for (int k = 0; k < BATCH; k++) acc += sD[k];
    out[0] = (float)(acc / BATCH);
  }
}

extern "C" void kernel_launch(void* const* d_in, const int* in_sizes, int n_in,
                              void* d_out, int out_size, void* d_ws, size_t ws_size,
                              hipStream_t stream) {
  const float* score1 = (const float*)d_in[0];
  const float* score2 = (const float*)d_in[1];
  const int*   mask   = (const int*)d_in[2];
  float* out = (float*)d_out;
  WS* ws = (WS*)d_ws;

  k_nms<<<NTILES, 256, 0, stream>>>(score1, score2, mask, ws);
  k_rankstamp<<<BATCH * 64, 256, 0, stream>>>(score1, mask, ws);
  k_final<<<1, 1024, 0, stream>>>(ws, out);
}

// Round 13
// 85.651 us; speedup vs baseline: 1.0479x; 1.0479x over previous
//
#include <hip/hip_runtime.h>
#include <math.h>

#define BATCH 16
#define H 1024
#define W 1024
#define NTILES 8192      // 16 img * 512 tiles (32x64)
#define NBANDS (NTILES * 4)   // 8-row x 64-col wave bands
#define CAP 4096
#define TOPK 2048
#define BCW 12           // per-band candidate cap (8-separation bound: 8)

struct WS {
  float pt1[NBANDS];               // per-band dense partials (always stored)
  int   pmc[NBANDS];
  int   band_cnt[NBANDS];          // always stored
  int   cand_count[BATCH];         // written by k_compact
  float corr_part[BATCH * 64];     // per (image,slice) stamp partial (always stored)
  float band_val[NBANDS * BCW];
  int   band_idx[NBANDS * BCW];
  float ccand_val[BATCH * CAP];    // compacted by k_compact (+3 zero pad)
  int   ccand_idx[BATCH * CAP];
};

// ks=7 sigma=1 normalized Gaussian (validated absmax 0.0 R1-R12)
__constant__ float GW[7] = {
  0.004433048175f, 0.054005582623f, 0.242036229376f, 0.399050279652f,
  0.242036229376f, 0.054005582623f, 0.004433048175f
};

__device__ __forceinline__ float4 max4(float4 a, float4 b) {
  float4 r;
  r.x = fmaxf(a.x, b.x); r.y = fmaxf(a.y, b.y);
  r.z = fmaxf(a.z, b.z); r.w = fmaxf(a.w, b.w);
  return r;
}

// ZERO s_barrier k_nms (R12, best measured: 71.5us). Unchanged.
__global__ __launch_bounds__(256, 5) void k_nms(const float* __restrict__ score1,
                                                const float* __restrict__ score2,
                                                const int* __restrict__ mask,
                                                WS* __restrict__ ws) {
  __shared__ float4 halo[4][22][21];   // per-wave slice: 22 rows x 20(+1 pad) f4
  const int tid = threadIdx.x;
  const int w = tid >> 6, l = tid & 63;

  const int t = (blockIdx.x & 7) * (NTILES / 8) + (blockIdx.x >> 3);
  const int b  = t >> 9;
  const int tt = t & 511;
  const int ty0 = (tt >> 4) << 5;
  const int tx0 = (tt & 15) << 6;
  const int by0 = ty0 + (w << 3);
  const size_t ibase = (size_t)b * ((size_t)H * W);
  const float* s2 = score2 + ibase;

  const int rl = l >> 3;
  const int c8 = l & 7;
  const size_t pb = ibase + (size_t)(by0 + rl) * W + tx0 + (c8 << 3);
  const float4 s1a = *(const float4*)(score1 + pb);
  const float4 s1b = *(const float4*)(score1 + pb + 4);
  const int4  mka = *(const int4*)(mask + pb);
  const int4  mkb = *(const int4*)(mask + pb + 4);

  float4 st[7]; int sr[7], sc[7];
  #pragma unroll
  for (int k = 0; k < 7; k++) {
    const int slot = l + (k << 6);
    if (slot < 440) {
      const int r = slot / 20, c = slot - r * 20;
      sr[k] = r; sc[k] = c;
      const int gy = by0 - 7 + r, gx = tx0 - 8 + (c << 2);
      const bool ok = (gy >= 0) & (gy < H) & (gx >= 0) & (gx < W);
      const int gyc = min(max(gy, 0), H - 1);
      const int gxc = ok ? gx : 0;
      float4 v = *(const float4*)(s2 + (size_t)gyc * W + gxc);
      if (!ok) v = make_float4(-INFINITY, -INFINITY, -INFINITY, -INFINITY);
      st[k] = v;
    }
  }

  float t1 = 0.f; int mcnt = 0; unsigned int mbits = 0;
  {
    const float sc_[8] = {s1a.x, s1a.y, s1a.z, s1a.w, s1b.x, s1b.y, s1b.z, s1b.w};
    const int   mm[8] = {mka.x, mka.y, mka.z, mka.w, mkb.x, mkb.y, mkb.z, mkb.w};
    #pragma unroll
    for (int j = 0; j < 8; j++) {
      if (mm[j]) { t1 = fmaf(sc_[j], sc_[j], t1); mcnt++; mbits |= (1u << j); }
    }
  }

  #pragma unroll
  for (int k = 0; k < 7; k++) {
    const int slot = l + (k << 6);
    if (slot < 440) halo[w][sr[k]][sc[k]] = st[k];
  }
  __builtin_amdgcn_wave_barrier();
  asm volatile("s_waitcnt lgkmcnt(0)" ::: "memory");
  __builtin_amdgcn_sched_barrier(0);

  float4 vr0, vr1, vr2, vr3;
  int R0 = 0, cg = 0;
  if (l < 40) {
    const int r2 = l / 20;
    cg = l - r2 * 20;
    R0 = r2 << 2;
    float4 core = halo[w][R0 + 3][cg];
    #pragma unroll
    for (int k = 4; k <= 14; k++) core = max4(core, halo[w][R0 + k][cg]);
    const float4 h0 = halo[w][R0][cg], h1 = halo[w][R0 + 1][cg], h2 = halo[w][R0 + 2][cg];
    const float4 h15 = halo[w][R0 + 15][cg], h16 = halo[w][R0 + 16][cg], h17 = halo[w][R0 + 17][cg];
    const float4 p2 = h2, p1 = max4(h1, p2), p0 = max4(h0, p1);
    const float4 sf15 = h15, sf16 = max4(sf15, h16), sf17 = max4(sf16, h17);
    vr0 = max4(core, p0);
    vr1 = max4(max4(core, p1), sf15);
    vr2 = max4(max4(core, p2), sf16);
    vr3 = max4(core, sf17);
  }
  const float4 cva = halo[w][rl + 7][(c8 << 1) + 2];
  const float4 cvb = halo[w][rl + 7][(c8 << 1) + 3];
  __builtin_amdgcn_wave_barrier();
  asm volatile("s_waitcnt lgkmcnt(0)" ::: "memory");
  __builtin_amdgcn_sched_barrier(0);

  if (l < 40) {
    halo[w][R0 + 0][cg] = vr0;
    halo[w][R0 + 1][cg] = vr1;
    halo[w][R0 + 2][cg] = vr2;
    halo[w][R0 + 3][cg] = vr3;
  }
  __builtin_amdgcn_wave_barrier();
  asm volatile("s_waitcnt lgkmcnt(0)" ::: "memory");
  __builtin_amdgcn_sched_barrier(0);

  float r[24];
  #pragma unroll
  for (int g = 0; g < 6; g++) {
    float4 v = halo[w][rl][(c8 << 1) + g];
    r[4 * g + 0] = v.x; r[4 * g + 1] = v.y; r[4 * g + 2] = v.z; r[4 * g + 3] = v.w;
  }
  float core = r[8];
  #pragma unroll
  for (int k = 9; k <= 15; k++) core = fmaxf(core, r[k]);
  const float q7 = r[7];
  const float q6 = fmaxf(r[6], q7);
  const float q5 = fmaxf(r[5], q6);
  const float q4 = fmaxf(r[4], q5);
  const float q3 = fmaxf(r[3], q4);
  const float q2 = fmaxf(r[2], q3);
  const float q1 = fmaxf(r[1], q2);
  float sa[7];
  sa[0] = r[16];
  #pragma unroll
  for (int k = 1; k < 7; k++) sa[k] = fmaxf(sa[k - 1], r[16 + k]);
  float pooled[8];
  pooled[0] = fmaxf(core, q1);
  pooled[1] = fmaxf(fmaxf(core, q2), sa[0]);
  pooled[2] = fmaxf(fmaxf(core, q3), sa[1]);
  pooled[3] = fmaxf(fmaxf(core, q4), sa[2]);
  pooled[4] = fmaxf(fmaxf(core, q5), sa[3]);
  pooled[5] = fmaxf(fmaxf(core, q6), sa[4]);
  pooled[6] = fmaxf(fmaxf(core, q7), sa[5]);
  pooled[7] = fmaxf(core, sa[6]);

  const float cc[8] = {cva.x, cva.y, cva.z, cva.w, cvb.x, cvb.y, cvb.z, cvb.w};
  int cj = -1; float cv = 0.f;
  #pragma unroll
  for (int j = 0; j < 8; j++) {
    if (((mbits >> j) & 1u) && cj < 0) {
      const float s = cc[j];
      if (s == pooled[j] && s > 0.f) { cj = j; cv = s; }
    }
  }
  const int band = (t << 2) + w;
  const unsigned long long bal = __ballot(cj >= 0);
  if (cj >= 0) {
    const int pos = (int)__popcll(bal & ((1ull << l) - 1ull));
    if (pos < BCW) {
      ws->band_val[band * BCW + pos] = cv;
      ws->band_idx[band * BCW + pos] = (by0 + rl) * W + tx0 + (c8 << 3) + cj;
    }
  }
  #pragma unroll
  for (int off = 32; off > 0; off >>= 1) {
    t1 += __shfl_down(t1, off);
    mcnt += __shfl_down(mcnt, off);
  }
  if (l == 0) {
    int nc = (int)__popcll(bal); if (nc > BCW) nc = BCW;
    ws->band_cnt[band] = nc;
    ws->pt1[band] = t1;
    ws->pmc[band] = mcnt;
  }
}

// One block per image: single compaction pass band arrays -> contiguous ccand.
__global__ __launch_bounds__(256) void k_compact(WS* __restrict__ ws) {
  const int b = blockIdx.x;
  const int tid = threadIdx.x;
  const int lane = tid & 63, w = tid >> 6;
  __shared__ int wt[4];

  const int base = b * 2048 + tid * 8;
  int c[8]; int csum = 0;
  #pragma unroll
  for (int u = 0; u < 8; u++) {
    int x = ws->band_cnt[base + u];
    if (x > BCW) x = BCW;
    c[u] = x; csum += x;
  }
  int v = csum;
  #pragma unroll
  for (int off = 1; off < 64; off <<= 1) {
    int u2 = __shfl_up(v, off);
    if (lane >= off) v += u2;
  }
  if (lane == 63) wt[w] = v;
  __syncthreads();
  int wo = 0;
  #pragma unroll
  for (int k = 0; k < 4; k++) if (k < w) wo += wt[k];
  const int excl = v - csum + wo;
  float* dv = ws->ccand_val + b * CAP;
  int*   di = ws->ccand_idx + b * CAP;
  if (tid == 255) {
    int tot = excl + csum;
    if (tot > CAP) tot = CAP;
    ws->cand_count[b] = tot;
    #pragma unroll
    for (int u = 0; u < 3; u++)
      if (tot + u < CAP) dv[tot + u] = 0.f;   // float4 pad (0 never matches: cands>0)
  }
  int off = excl;
  #pragma unroll
  for (int u = 0; u < 8; u++) {
    const float* sv = ws->band_val + (size_t)(base + u) * BCW;
    const int*   si = ws->band_idx + (size_t)(base + u) * BCW;
    for (int j = 0; j < c[u]; j++) {
      if (off < CAP) { dv[off] = sv[j]; di[off] = si[j]; }
      off++;
    }
  }
}

// Exact-rank + stamp from compacted arrays (R7-style dense loads).
__global__ __launch_bounds__(256, 4) void k_rankstamp(const float* __restrict__ score1,
                                                      const int* __restrict__ mask,
                                                      WS* __restrict__ ws) {
  const int blk = (blockIdx.x & 7) * 128 + (blockIdx.x >> 3);
  const int b = blk >> 6;
  const int slice = blk & 63;
  int n = ws->cand_count[b]; if (n > CAP) n = CAP;
  const int i0 = slice << 6;
  if (i0 >= n) {
    if (threadIdx.x == 0) ws->corr_part[b * 64 + slice] = 0.f;
    return;
  }
  __shared__ __align__(16) float sval[CAP];
  __shared__ __align__(16) int   sidx[CAP];
  __shared__ int   s_prank[4][64];
  __shared__ int   s_keys[64];
  __shared__ int   s_nk;
  __shared__ float cred[4];
  const int tid = threadIdx.x;
  const int w = tid >> 6, l = tid & 63;
  const int nf4 = (n + 3) >> 2;

  const float4* gv = (const float4*)(ws->ccand_val + b * CAP);
  const int4*   gi = (const int4*)(ws->ccand_idx + b * CAP);
  for (int j = tid; j < nf4; j += 256) {
    ((float4*)sval)[j] = gv[j];
    ((int4*)sidx)[j]   = gi[j];
  }
  __syncthreads();

  const float vi = sval[i0 + l];
  const int   xi = sidx[i0 + l];
  const int q = (nf4 + 3) >> 2;
  int lo = w * q; if (lo > nf4) lo = nf4;
  int hi = lo + q; if (hi > nf4) hi = nf4;
  int rank = 0;
  int j = lo;
  for (; j + 4 <= hi; j += 4) {
    #pragma unroll
    for (int u = 0; u < 4; u++) {
      const float4 vv = ((const float4*)sval)[j + u];
      const int4  iv = ((const int4*)sidx)[j + u];
      rank += (vv.x > vi) + (vv.y > vi) + (vv.z > vi) + (vv.w > vi);
      rank += (vv.x == vi && iv.x < xi);
      rank += (vv.y == vi && iv.y < xi);
      rank += (vv.z == vi && iv.z < xi);
      rank += (vv.w == vi && iv.w < xi);
    }
  }
  for (; j < hi; j++) {
    const float4 vv = ((const float4*)sval)[j];
    const int4  iv = ((const int4*)sidx)[j];
    rank += (vv.x > vi) + (vv.y > vi) + (vv.z > vi) + (vv.w > vi);
    rank += (vv.x == vi && iv.x < xi);
    rank += (vv.y == vi && iv.y < xi);
    rank += (vv.z == vi && iv.z < xi);
    rank += (vv.w == vi && iv.w < xi);
  }
  s_prank[w][l] = rank;
  __syncthreads();

  if (tid < 64) {
    const int rtot = s_prank[0][tid] + s_prank[1][tid] + s_prank[2][tid] + s_prank[3][tid];
    const bool sel = (i0 + tid < n) && (rtot < TOPK);
    const unsigned long long bal = __ballot(sel);
    if (sel) {
      const int pos = __popcll(bal & ((1ull << tid) - 1ull));
      s_keys[pos] = sidx[i0 + tid];
    }
    if (tid == 0) s_nk = (int)__popcll(bal);
  }
  __syncthreads();
  const int nk = s_nk;

  float contrib = 0.f;
  const int sub = tid & 7;
  const size_t ib2 = (size_t)b * ((size_t)H * W);
  #pragma unroll
  for (int rnd = 0; rnd < 2; rnd++) {
    const int k = (tid >> 3) + (rnd << 5);
    if (k < nk && sub < 7) {
      const int ck = s_keys[k];
      const int cy = ck >> 10, cx = ck & 1023;
      const int py = cy + sub - 3;
      const float wy = GW[sub] * ((py >= 0 && py < H) ? 1.f : 0.f);
      const int pyc = min(max(py, 0), H - 1);
      const float* s1r = score1 + ib2 + (size_t)pyc * W;
      const int*   mr  = mask   + ib2 + (size_t)pyc * W;
      #pragma unroll
      for (int dx = -3; dx <= 3; dx++) {
        const int px = cx + dx;
        const float wv = wy * GW[dx + 3] * ((px >= 0 && px < W) ? 1.f : 0.f);
        const int pxc = min(max(px, 0), W - 1);
        const float mf = (mr[pxc] != 0) ? 1.f : 0.f;
        contrib += mf * wv * (wv - 2.f * s1r[pxc]);
      }
    }
  }
  #pragma unroll
  for (int off2 = 32; off2 > 0; off2 >>= 1) contrib += __shfl_down(contrib, off2);
  if (l == 0) cred[w] = contrib;
  __syncthreads();
  if (tid == 0)
    ws->corr_part[b * 64 + slice] = (cred[0] + cred[1]) + (cred[2] + cred[3]);
}

// One block, 1024 threads: wave b reduces image b's partials.
__global__ __launch_bounds__(1024) void k_final(WS* __restrict__ ws, float* __restrict__ out) {
  const int tid = threadIdx.x;
  const int b = tid >> 6, l = tid & 63;
  __shared__ double sD[BATCH];

  double tsum = 0.0; long long msum = 0;
  const float4* pv = (const float4*)(ws->pt1 + b * 2048);
  const int4*   pm = (const int4*)(ws->pmc + b * 2048);
  #pragma unroll
  for (int k = 0; k < 8; k++) {
    const float4 f = pv[l + (k << 6)];
    const int4   m = pm[l + (k << 6)];
    tsum += (double)f.x + (double)f.y + (double)f.z + (double)f.w;
    msum += (long long)(m.x + m.y + m.z + m.w);
  }
  double csum = (double)ws->corr_part[b * 64 + l];
  #pragma unroll
  for (int off = 32; off > 0; off >>= 1) {
    tsum += __shfl_down(tsum, off);
    msum += __shfl_down(msum, off);
    csum += __shfl_down(csum, off);
  }
  if (l == 0) {
    double denom = (double)msum;
    if (denom < 1e-8) denom = 1e-8;
    sD[b] = (tsum + csum) / denom;
  }
  __syncthreads();
  if (tid == 0) {
    double acc = 0.0;
    #pragma unroll
    for (int k = 0; k < BATCH; k++) acc += sD[k];
    out[0] = (float)(acc / BATCH);
  }
}

extern "C" void kernel_launch(void* const* d_in, const int* in_sizes, int n_in,
                              void* d_out, int out_size, void* d_ws, size_t ws_size,
                              hipStream_t stream) {
  const float* score1 = (const float*)d_in[0];
  const float* score2 = (const float*)d_in[1];
  const int*   mask   = (const int*)d_in[2];
  float* out = (float*)d_out;
  WS* ws = (WS*)d_ws;

  k_nms<<<NTILES, 256, 0, stream>>>(score1, score2, mask, ws);
  k_compact<<<BATCH, 256, 0, stream>>>(ws);
  k_rankstamp<<<BATCH * 64, 256, 0, stream>>>(score1, mask, ws);
  k_final<<<1, 1024, 0, stream>>>(ws, out);
}